// Round 8
// baseline (287.664 us; speedup 1.0000x reference)
//
#include <hip/hip_runtime.h>
#include <hip/hip_bf16.h>
#include <hip/hip_fp8.h>
#include <math.h>
#include <string.h>

#define B 32
#define CIN 22
#define T 5000
#define EMB 64
#define P 100
#define HOP 25
#define OC 40
#define FC 120
#define NBIN 11
#define NFR 200

#define TCH 256
#define CROWS 304     // TCH + 24 halo each side
#define RS8 40        // bytes per fp8 xs row (32 channel slots + 8 pad; 10 dwords -> bank-spread)
#define NCONV (20 * B)   // 640 conv blocks

#define XPAD 5128
#define TWROW 24

// planar feats: 3 planes of [B][T][40] bf16
#define PLANE ((size_t)B * T * OC)

typedef __attribute__((ext_vector_type(4))) float f32x4;

__device__ __forceinline__ unsigned short f2bf(float f) {
  unsigned u = __float_as_uint(f);
  unsigned r = (u + 0x7FFFu + ((u >> 16) & 1u)) >> 16;
  return (unsigned short)r;
}
__device__ __forceinline__ float bf2f(unsigned short u) {
  return __uint_as_float(((unsigned)u) << 16);
}
__device__ __forceinline__ unsigned char f2fp8(float f) {
  __hip_fp8_e4m3 q(f);
  return (unsigned char)q.__x;
}
__device__ __forceinline__ float fast_elu(float y) {
  return y > 0.f ? y : (__builtin_amdgcn_exp2f(y * 1.44269504088896340736f) - 1.0f);
}
__device__ __forceinline__ unsigned pack2bf(float a, float b) {
  __hip_bfloat162 h = __float22bfloat162_rn(make_float2(a, b));
  unsigned u;
  memcpy(&u, &h, 4);
  return u;
}
__device__ __forceinline__ float wave_sum_f(float v) {
  #pragma unroll
  for (int off = 1; off < 64; off <<= 1) v += __shfl_xor(v, off);
  return v;
}
__device__ __forceinline__ int wave_sum_i(int v) {
  #pragma unroll
  for (int off = 1; off < 64; off <<= 1) v += __shfl_xor(v, off);
  return v;
}

// ---------------- K1: setup = fp8 weight-pack + twiddles + affine ----------------
struct SetupArgs {
  const float* w1[3]; const float* b1[3]; const float* w2[3]; const float* b2[3];
  const float* g[3];  const float* bt[3]; const float* m[3];  const float* v[3];
  unsigned char* pw8;
  float* A; float* Bc; float* tw;   // tw: [128][TWROW]
};

__global__ __launch_bounds__(256) void setup_all(SetupArgs args) {
  int bx = blockIdx.x;
  int tid = threadIdx.x;
  if (bx < 63) {
    // pack fused conv weights into fp8 MFMA A-fragment order.
    int id = bx * 256 + tid;          // fragment-lane id
    if (id < 15936) {                 // 249 fragments * 64 lanes
      int fi = id >> 6;               // global fragment index 0..248
      int lane = id & 63;
      int s, KS, fl;
      if (fi < 27)       { s = 0; KS = 9;  fl = fi; }
      else if (fi < 102) { s = 1; KS = 25; fl = fi - 27; }
      else               { s = 2; KS = 49; fl = fi - 102; }
      int k = fl / 3, ot = fl - k * 3;
      int m = lane & 15, hb = (lane >> 4) << 3;
      int o = ot * 16 + m;
      float val[8];
      #pragma unroll
      for (int j = 0; j < 8; ++j) val[j] = 0.f;
      if (o < OC && hb < CIN) {
        const float* w1 = args.w1[s];
        const float* w2 = args.w2[s];
        if (hb + 8 <= CIN) {          // hb = 0 or 8: all 8 h valid
          for (int i = 0; i < OC; ++i) {
            float wv = w1[i * KS + k];
            const float* w2r = w2 + (size_t)(o * OC + i) * CIN + hb;
            float2 a0 = *(const float2*)(w2r + 0);
            float2 a1 = *(const float2*)(w2r + 2);
            float2 a2 = *(const float2*)(w2r + 4);
            float2 a3 = *(const float2*)(w2r + 6);
            val[0] = fmaf(a0.x, wv, val[0]); val[1] = fmaf(a0.y, wv, val[1]);
            val[2] = fmaf(a1.x, wv, val[2]); val[3] = fmaf(a1.y, wv, val[3]);
            val[4] = fmaf(a2.x, wv, val[4]); val[5] = fmaf(a2.y, wv, val[5]);
            val[6] = fmaf(a3.x, wv, val[6]); val[7] = fmaf(a3.y, wv, val[7]);
          }
        } else {                      // hb = 16: h 16..21 valid (j 0..5)
          for (int i = 0; i < OC; ++i) {
            float wv = w1[i * KS + k];
            const float* w2r = w2 + (size_t)(o * OC + i) * CIN + hb;
            float2 a0 = *(const float2*)(w2r + 0);
            float2 a1 = *(const float2*)(w2r + 2);
            float2 a2 = *(const float2*)(w2r + 4);
            val[0] = fmaf(a0.x, wv, val[0]); val[1] = fmaf(a0.y, wv, val[1]);
            val[2] = fmaf(a1.x, wv, val[2]); val[3] = fmaf(a1.y, wv, val[3]);
            val[4] = fmaf(a2.x, wv, val[4]); val[5] = fmaf(a2.y, wv, val[5]);
          }
        }
      }
      unsigned char bytes[8];
      #pragma unroll
      for (int j = 0; j < 8; ++j) bytes[j] = f2fp8(val[j]);
      long long pk;
      memcpy(&pk, bytes, 8);
      *(long long*)(args.pw8 + (size_t)fi * 512 + lane * 8) = pk;
    }
  } else if (bx < 69) {
    int id = (bx - 63) * 256 + tid;
    if (id < 1408) {
      int n = id & 127, k = id >> 7;
      const double PI = 3.14159265358979323846;
      double ang = -2.0 * PI * (double)((k + 5) * n) / 128.0;
      double win = 0.5 * (1.0 - cos(2.0 * PI * (double)n / 128.0));
      args.tw[n * TWROW + 2 * k]     = (float)(cos(ang) * win);
      args.tw[n * TWROW + 2 * k + 1] = (float)(sin(ang) * win);
    } else if (id < 1536) {
      int n = id - 1408;
      args.tw[n * TWROW + 22] = 0.f;
      args.tw[n * TWROW + 23] = 0.f;
    }
  } else {
    if (tid < 120) {
      int s = tid / 40, o = tid - s * 40;
      const float* w2 = args.w2[s];
      float sc = args.g[s][o] / sqrtf(args.v[s][o] + 1e-5f);
      float cc = args.b2[s][o];
      for (int i = 0; i < OC; ++i) {
        float sh = 0.f;
        for (int h = 0; h < CIN; ++h) sh += w2[(o * OC + i) * CIN + h];
        cc = fmaf(args.b1[s][i], sh, cc);
      }
      args.A[tid] = sc;
      args.Bc[tid] = cc * sc + (args.bt[s][o] - args.m[s][o] * sc);
    }
  }
}

// ---------------- K2: fused stft + fp8 conv (independent halves share the machine) ----------------
// conv blocks 0..639 dispatch first (the MFMA long pole); stft blocks 640..1343
// fill the CUs with VALU waves -> MFMA and VALU pipes co-schedule (time ~ max).
struct SCSmem {
  union {
    float xsh[XPAD];                  // stft staging (20512 B)
    unsigned char xs8[CROWS * RS8];   // conv fp8 tile (12160 B)
  };
};

template <int KS, int FB, int SBASE>
__device__ __forceinline__ void scale_body(const unsigned char* __restrict__ xs8,
                                           const unsigned char* __restrict__ pw8,
                                           const float* __restrict__ Aff,
                                           const float* __restrict__ Bff,
                                           unsigned short* __restrict__ fplane,
                                           int b, int t0, int wt0, int lane) {
  constexpr int PAD = (KS - 1) / 2;
  const int n = lane & 15, q = lane >> 4;
  f32x4 acc[3][4];
  #pragma unroll
  for (int ot = 0; ot < 3; ++ot)
    #pragma unroll
    for (int ti = 0; ti < 4; ++ti)
      acc[ot][ti] = (f32x4){0.f, 0.f, 0.f, 0.f};

  const unsigned char* pws = pw8 + (size_t)FB * 512 + lane * 8;
  const unsigned char* xrow = xs8 + (24 - PAD + wt0 + n) * RS8 + q * 8;
  // depth-1 software pipeline on BOTH operand streams; setprio(1) biases the
  // conv waves over co-resident stft VALU waves while MFMAs are in flight.
  __builtin_amdgcn_s_setprio(1);
  long long A0 = *(const long long*)(pws);
  long long A1 = *(const long long*)(pws + 512);
  long long A2 = *(const long long*)(pws + 1024);
  long long B0 = *(const long long*)(xrow);
  long long B1 = *(const long long*)(xrow + 16 * RS8);
  long long B2 = *(const long long*)(xrow + 32 * RS8);
  long long B3 = *(const long long*)(xrow + 48 * RS8);
  #pragma unroll 2
  for (int k = 0; k < KS - 1; ++k) {
    const unsigned char* p = pws + (size_t)(k + 1) * 1536;
    long long nA0 = *(const long long*)(p);
    long long nA1 = *(const long long*)(p + 512);
    long long nA2 = *(const long long*)(p + 1024);
    const unsigned char* xr = xrow + (k + 1) * RS8;
    long long nB0 = *(const long long*)(xr);
    long long nB1 = *(const long long*)(xr + 16 * RS8);
    long long nB2 = *(const long long*)(xr + 32 * RS8);
    long long nB3 = *(const long long*)(xr + 48 * RS8);
    acc[0][0] = __builtin_amdgcn_mfma_f32_16x16x32_fp8_fp8(A0, B0, acc[0][0], 0, 0, 0);
    acc[1][0] = __builtin_amdgcn_mfma_f32_16x16x32_fp8_fp8(A1, B0, acc[1][0], 0, 0, 0);
    acc[2][0] = __builtin_amdgcn_mfma_f32_16x16x32_fp8_fp8(A2, B0, acc[2][0], 0, 0, 0);
    acc[0][1] = __builtin_amdgcn_mfma_f32_16x16x32_fp8_fp8(A0, B1, acc[0][1], 0, 0, 0);
    acc[1][1] = __builtin_amdgcn_mfma_f32_16x16x32_fp8_fp8(A1, B1, acc[1][1], 0, 0, 0);
    acc[2][1] = __builtin_amdgcn_mfma_f32_16x16x32_fp8_fp8(A2, B1, acc[2][1], 0, 0, 0);
    acc[0][2] = __builtin_amdgcn_mfma_f32_16x16x32_fp8_fp8(A0, B2, acc[0][2], 0, 0, 0);
    acc[1][2] = __builtin_amdgcn_mfma_f32_16x16x32_fp8_fp8(A1, B2, acc[1][2], 0, 0, 0);
    acc[2][2] = __builtin_amdgcn_mfma_f32_16x16x32_fp8_fp8(A2, B2, acc[2][2], 0, 0, 0);
    acc[0][3] = __builtin_amdgcn_mfma_f32_16x16x32_fp8_fp8(A0, B3, acc[0][3], 0, 0, 0);
    acc[1][3] = __builtin_amdgcn_mfma_f32_16x16x32_fp8_fp8(A1, B3, acc[1][3], 0, 0, 0);
    acc[2][3] = __builtin_amdgcn_mfma_f32_16x16x32_fp8_fp8(A2, B3, acc[2][3], 0, 0, 0);
    A0 = nA0; A1 = nA1; A2 = nA2;
    B0 = nB0; B1 = nB1; B2 = nB2; B3 = nB3;
  }
  // peeled last tap (no prefetch)
  acc[0][0] = __builtin_amdgcn_mfma_f32_16x16x32_fp8_fp8(A0, B0, acc[0][0], 0, 0, 0);
  acc[1][0] = __builtin_amdgcn_mfma_f32_16x16x32_fp8_fp8(A1, B0, acc[1][0], 0, 0, 0);
  acc[2][0] = __builtin_amdgcn_mfma_f32_16x16x32_fp8_fp8(A2, B0, acc[2][0], 0, 0, 0);
  acc[0][1] = __builtin_amdgcn_mfma_f32_16x16x32_fp8_fp8(A0, B1, acc[0][1], 0, 0, 0);
  acc[1][1] = __builtin_amdgcn_mfma_f32_16x16x32_fp8_fp8(A1, B1, acc[1][1], 0, 0, 0);
  acc[2][1] = __builtin_amdgcn_mfma_f32_16x16x32_fp8_fp8(A2, B1, acc[2][1], 0, 0, 0);
  acc[0][2] = __builtin_amdgcn_mfma_f32_16x16x32_fp8_fp8(A0, B2, acc[0][2], 0, 0, 0);
  acc[1][2] = __builtin_amdgcn_mfma_f32_16x16x32_fp8_fp8(A1, B2, acc[1][2], 0, 0, 0);
  acc[2][2] = __builtin_amdgcn_mfma_f32_16x16x32_fp8_fp8(A2, B2, acc[2][2], 0, 0, 0);
  acc[0][3] = __builtin_amdgcn_mfma_f32_16x16x32_fp8_fp8(A0, B3, acc[0][3], 0, 0, 0);
  acc[1][3] = __builtin_amdgcn_mfma_f32_16x16x32_fp8_fp8(A1, B3, acc[1][3], 0, 0, 0);
  acc[2][3] = __builtin_amdgcn_mfma_f32_16x16x32_fp8_fp8(A2, B3, acc[2][3], 0, 0, 0);
  __builtin_amdgcn_s_setprio(0);

  #pragma unroll
  for (int ot = 0; ot < 3; ++ot) {
    int obase = ot * 16 + q * 4;
    if (obase < OC) {
      float Av0 = Aff[SBASE + obase + 0], Bv0 = Bff[SBASE + obase + 0];
      float Av1 = Aff[SBASE + obase + 1], Bv1 = Bff[SBASE + obase + 1];
      float Av2 = Aff[SBASE + obase + 2], Bv2 = Bff[SBASE + obase + 2];
      float Av3 = Aff[SBASE + obase + 3], Bv3 = Bff[SBASE + obase + 3];
      #pragma unroll
      for (int ti = 0; ti < 4; ++ti) {
        int tt = t0 + wt0 + ti * 16 + n;
        if (tt < T) {
          uint2 pk;
          pk.x = pack2bf(fast_elu(fmaf(acc[ot][ti][0], Av0, Bv0)),
                         fast_elu(fmaf(acc[ot][ti][1], Av1, Bv1)));
          pk.y = pack2bf(fast_elu(fmaf(acc[ot][ti][2], Av2, Bv2)),
                         fast_elu(fmaf(acc[ot][ti][3], Av3, Bv3)));
          *reinterpret_cast<uint2*>(fplane + (size_t)(b * T + tt) * OC + obase) = pk;
        }
      }
    }
  }
}

struct SCArgs {
  const float* x;
  const unsigned char* pw8;
  const float* Aff; const float* Bff;
  unsigned short* feats;
  const float* tw;
  float* comb;
};

__global__ __launch_bounds__(256) void stft_conv(SCArgs args) {
  __shared__ SCSmem sm;
  int bx = blockIdx.x;
  int tid = threadIdx.x;
  if (bx < NCONV) {
    // ---- conv: 20 chunks of 256 t per batch; 4 waves, 64 t per wave ----
    int b = bx / 20, t0 = (bx - b * 20) * TCH;
    for (int i = tid; i < CROWS * RS8 / 4; i += 256)
      reinterpret_cast<unsigned*>(sm.xs8)[i] = 0u;
    __syncthreads();
    for (int idx = tid; idx < CIN * CROWS; idx += 256) {
      int h = idx / CROWS, tl = idx - h * CROWS;
      int gt = t0 - 24 + tl;
      float v = (gt >= 0 && gt < T) ? args.x[(size_t)(b * CIN + h) * T + gt] : 0.f;
      sm.xs8[tl * RS8 + h] = f2fp8(v);
    }
    __syncthreads();
    int wv = tid >> 6, lane = tid & 63;
    int wt0 = wv * 64;
    scale_body<9, 0, 0>(sm.xs8, args.pw8, args.Aff, args.Bff, args.feats, b, t0, wt0, lane);
    scale_body<25, 27, 40>(sm.xs8, args.pw8, args.Aff, args.Bff, args.feats + PLANE, b, t0, wt0, lane);
    scale_body<49, 102, 80>(sm.xs8, args.pw8, args.Aff, args.Bff, args.feats + 2 * PLANE, b, t0, wt0, lane);
  } else {
    // ---- stft: one block per (batch, channel) ----
    int bc = bx - NCONV;
    const float* xr = args.x + (size_t)bc * T;
    for (int i = tid; i < XPAD; i += 256) {
      int mm = i - 64;
      mm = (mm < 0) ? -mm : mm;
      mm = (mm >= T) ? (2 * T - 2 - mm) : mm;
      sm.xsh[i] = xr[mm];
    }
    __syncthreads();
    int fr = tid;
    if (fr < NFR) {
      float cr[NBIN], ci[NBIN];
      #pragma unroll
      for (int k = 0; k < NBIN; ++k) { cr[k] = 0.f; ci[k] = 0.f; }
      const float* xw = sm.xsh + fr * HOP;
      const float* tw = args.tw;
      #pragma unroll 2
      for (int n = 0; n < 128; ++n) {
        float xv = xw[n];
        const float4* t4 = reinterpret_cast<const float4*>(tw + n * TWROW);
        float4 w0 = t4[0], w1 = t4[1], w2 = t4[2], w3 = t4[3], w4 = t4[4], w5 = t4[5];
        cr[0] = fmaf(xv, w0.x, cr[0]); ci[0] = fmaf(xv, w0.y, ci[0]);
        cr[1] = fmaf(xv, w0.z, cr[1]); ci[1] = fmaf(xv, w0.w, ci[1]);
        cr[2] = fmaf(xv, w1.x, cr[2]); ci[2] = fmaf(xv, w1.y, ci[2]);
        cr[3] = fmaf(xv, w1.z, cr[3]); ci[3] = fmaf(xv, w1.w, ci[3]);
        cr[4] = fmaf(xv, w2.x, cr[4]); ci[4] = fmaf(xv, w2.y, ci[4]);
        cr[5] = fmaf(xv, w2.z, cr[5]); ci[5] = fmaf(xv, w2.w, ci[5]);
        cr[6] = fmaf(xv, w3.x, cr[6]); ci[6] = fmaf(xv, w3.y, ci[6]);
        cr[7] = fmaf(xv, w3.z, cr[7]); ci[7] = fmaf(xv, w3.w, ci[7]);
        cr[8] = fmaf(xv, w4.x, cr[8]); ci[8] = fmaf(xv, w4.y, ci[8]);
        cr[9] = fmaf(xv, w4.z, cr[9]); ci[9] = fmaf(xv, w4.w, ci[9]);
        cr[10] = fmaf(xv, w5.x, cr[10]); ci[10] = fmaf(xv, w5.y, ci[10]);
      }
      float p[NBIN];
      #pragma unroll
      for (int k = 0; k < NBIN; ++k) p[k] = cr[k] * cr[k] + ci[k] * ci[k];
      float beta = 0.f;
      #pragma unroll
      for (int k = 2; k < NBIN; ++k) beta += p[k];
      args.comb[bc * NFR + fr] = 0.5f * (p[0] + p[1]) + beta * (1.f / 9.f);
    }
  }
}

// ---------------- K3: act_grid (32 blocks; byte-identical to validated pipeline) ----------------
struct ActSmem {
  float cl[CIN * NFR];
  float actL[NFR];
  float aiL[P];
  float fL[P];
  int giL[P];
  int sI[P];
  float red;
};

struct ActArgs {
  const float* comb;
  const float* aw1; const float* ab1;
  const float* ag;  const float* abt;
  const float* am;  const float* av;
  const float* aw2; const float* ab2;
  float* out_grid; float* out_acti;
  int* ends_i; int* grid_i;
};

__global__ __launch_bounds__(256) void act_grid(ActArgs args) {
  __shared__ ActSmem sm;
  int b = blockIdx.x;
  int tid = threadIdx.x;
  for (int i = tid; i < CIN * NFR; i += 256) sm.cl[i] = args.comb[b * CIN * NFR + i];
  __syncthreads();
  int t = tid;
  if (t < NFR) {
    float z = args.ab2[0];
    for (int o = 0; o < 11; ++o) {
      float s = args.ab1[o];
      for (int i = 0; i < CIN; ++i) {
        const float* wr = args.aw1 + o * 66 + i * 3;
        const float* crow = sm.cl + i * NFR;
        if (t > 0)       s = fmaf(wr[0], crow[t - 1], s);
        s = fmaf(wr[1], crow[t], s);
        if (t < NFR - 1) s = fmaf(wr[2], crow[t + 1], s);
      }
      float rs = 1.0f / sqrtf(args.av[o] + 1e-5f);
      float y = (s - args.am[o]) * rs * args.ag[o] + args.abt[o];
      y = fmaxf(y, 0.f);
      z = fmaf(args.aw2[o], y, z);
    }
    sm.actL[t] = 1.f / (1.f + expf(-z));
  }
  __syncthreads();
  if (t < P) {
    float ai = 0.5f * (sm.actL[2 * t] + sm.actL[2 * t + 1]);
    sm.aiL[t] = ai;
    args.out_acti[b * P + t] = ai;
    sm.fL[t] = 1.f / (ai + 1e-6f);
  }
  __syncthreads();
  if (t < 64) {
    float v = sm.fL[t] + ((t + 64 < P) ? sm.fL[t + 64] : 0.f);
    v = wave_sum_f(v);
    if (t == 0) sm.red = v;
  }
  __syncthreads();
  float sw = sm.red;
  if (t < P) {
    float ggv = (sm.fL[t] / sw) * 5000.f;
    ggv = fminf(fmaxf(ggv, 10.f), 100.f);
    sm.fL[t] = ggv;
  }
  __syncthreads();
  if (t < 64) {
    float v = sm.fL[t] + ((t + 64 < P) ? sm.fL[t + 64] : 0.f);
    v = wave_sum_f(v);
    if (t == 0) sm.red = v;
  }
  __syncthreads();
  float r = 5000.f / sm.red;
  if (t < P) sm.giL[t] = (int)rintf(sm.fL[t] * r);
  __syncthreads();
  if (t < 64) {
    int v = sm.giL[t] + ((t + 64 < P) ? sm.giL[t + 64] : 0);
    v = wave_sum_i(v);
    if (t == 0) sm.red = __int_as_float(v);
  }
  __syncthreads();
  if (t == P - 1) sm.giL[P - 1] += 5000 - __float_as_int(sm.red);
  __syncthreads();
  if (t < P) sm.giL[t] = min(max(sm.giL[t], 10), 100);
  __syncthreads();
  if (t < 64) {
    int v = sm.giL[t] + ((t + 64 < P) ? sm.giL[t + 64] : 0);
    v = wave_sum_i(v);
    if (t == 0) sm.red = __int_as_float(v);
  }
  __syncthreads();
  if (t == P - 1) sm.giL[P - 1] += 5000 - __float_as_int(sm.red);
  __syncthreads();
  if (t < P) sm.sI[t] = max(sm.giL[t], 10);
  __syncthreads();
  #pragma unroll
  for (int off = 1; off < P; off <<= 1) {
    int v = 0;
    if (t < P && t >= off) v = sm.sI[t - off];
    __syncthreads();
    if (t < P) sm.sI[t] += v;
    __syncthreads();
  }
  if (t < P) {
    int g2 = max(sm.giL[t], 10);
    args.out_grid[b * P + t] = (float)g2;
    args.grid_i[b * P + t] = g2;
    args.ends_i[b * P + t] = sm.sI[t];
  }
}

// ---------------- K4: ragged avg+max pool + projection (planar feats) ----------------
__global__ __launch_bounds__(256) void pool_proj(const unsigned short* __restrict__ feats,
                                                 const int* __restrict__ ends_i,
                                                 const int* __restrict__ grid_i,
                                                 const float* __restrict__ proj_w,
                                                 const float* __restrict__ proj_b,
                                                 float* __restrict__ out_emb) {
  int bp = blockIdx.x;
  int b = bp / P;
  int end = ends_i[bp];
  int gr = grid_i[bp];
  int start = end - gr;
  __shared__ float lds_s[16 * FC];
  __shared__ float lds_m[16 * FC];
  __shared__ float pooled[FC];
  int tid = threadIdx.x;
  bool valid = (end <= T);
  int g = tid % 15;
  int r = tid / 15;
  if (valid && r < 16) {
    float s[8], m[8];
    #pragma unroll
    for (int j = 0; j < 8; ++j) { s[j] = 0.f; m[j] = -INFINITY; }
    // plane = g/5, channel offset within plane = (g%5)*8; logical channel
    // index g*8+j is unchanged vs the interleaved layout.
    int pl = g / 5, g2 = g - pl * 5;
    const unsigned short* base = feats + (size_t)pl * PLANE + (size_t)(b * T + start) * OC + g2 * 8;
    for (int i = r; i < gr; i += 16) {
      uint4 u4 = *reinterpret_cast<const uint4*>(base + (size_t)i * OC);
      unsigned w[4] = {u4.x, u4.y, u4.z, u4.w};
      #pragma unroll
      for (int j = 0; j < 4; ++j) {
        float v0 = bf2f((unsigned short)(w[j] & 0xffffu));
        float v1 = bf2f((unsigned short)(w[j] >> 16));
        s[2 * j] += v0; s[2 * j + 1] += v1;
        m[2 * j] = fmaxf(m[2 * j], v0); m[2 * j + 1] = fmaxf(m[2 * j + 1], v1);
      }
    }
    #pragma unroll
    for (int j = 0; j < 8; ++j) {
      lds_s[r * FC + g * 8 + j] = s[j];
      lds_m[r * FC + g * 8 + j] = m[j];
    }
  }
  __syncthreads();
  if (tid < FC) {
    if (valid) {
      float s = 0.f, mx = -INFINITY;
      #pragma unroll
      for (int rr = 0; rr < 16; ++rr) {
        s += lds_s[rr * FC + tid];
        mx = fmaxf(mx, lds_m[rr * FC + tid]);
      }
      pooled[tid] = s / (float)gr + mx;
    } else {
      pooled[tid] = 0.f;
    }
  }
  __syncthreads();
  if (tid < EMB) {
    float e = proj_b[tid];
    const float* wr = proj_w + tid * FC;
    #pragma unroll 8
    for (int c = 0; c < FC; ++c) e = fmaf(wr[c], pooled[c], e);
    out_emb[(size_t)bp * EMB + tid] = e;
  }
}

extern "C" void kernel_launch(void* const* d_in, const int* in_sizes, int n_in,
                              void* d_out, int out_size, void* d_ws, size_t ws_size,
                              hipStream_t stream) {
  const float* x = (const float*)d_in[0];
  const float* aw1 = (const float*)d_in[25];
  const float* ab1 = (const float*)d_in[26];
  const float* ag  = (const float*)d_in[27];
  const float* abt = (const float*)d_in[28];
  const float* am  = (const float*)d_in[29];
  const float* av  = (const float*)d_in[30];
  const float* aw2 = (const float*)d_in[31];
  const float* ab2 = (const float*)d_in[32];
  const float* proj_w = (const float*)d_in[33];
  const float* proj_b = (const float*)d_in[34];

  float* wsf = (float*)d_ws;
  float* A    = wsf;                 // 120
  float* Bc   = wsf + 120;           // 120
  float* tw   = wsf + 240;           // 3072
  float* comb = wsf + 4096;          // 140800
  int* ends_i = (int*)(wsf + 144896);
  int* grid_i = (int*)(wsf + 148096);
  unsigned char* pw8 = (unsigned char*)(wsf + 151296);      // 127488 bytes (8B-aligned)
  unsigned short* feats = (unsigned short*)(wsf + 215040);  // 3 planes x B*T*40 bf16 (38.4 MB)

  float* out      = (float*)d_out;
  float* out_emb  = out;
  float* out_grid = out + 204800;
  float* out_acti = out + 208000;

  SetupArgs sa;
  for (int s = 0; s < 3; ++s) {
    sa.w1[s] = (const float*)d_in[1 + 8 * s];
    sa.b1[s] = (const float*)d_in[2 + 8 * s];
    sa.w2[s] = (const float*)d_in[3 + 8 * s];
    sa.b2[s] = (const float*)d_in[4 + 8 * s];
    sa.g[s]  = (const float*)d_in[5 + 8 * s];
    sa.bt[s] = (const float*)d_in[6 + 8 * s];
    sa.m[s]  = (const float*)d_in[7 + 8 * s];
    sa.v[s]  = (const float*)d_in[8 + 8 * s];
  }
  sa.pw8 = pw8; sa.A = A; sa.Bc = Bc; sa.tw = tw;

  SCArgs sc;
  sc.x = x; sc.pw8 = pw8; sc.Aff = A; sc.Bff = Bc; sc.feats = feats;
  sc.tw = tw; sc.comb = comb;

  ActArgs aa;
  aa.comb = comb; aa.aw1 = aw1; aa.ab1 = ab1; aa.ag = ag; aa.abt = abt;
  aa.am = am; aa.av = av; aa.aw2 = aw2; aa.ab2 = ab2;
  aa.out_grid = out_grid; aa.out_acti = out_acti;
  aa.ends_i = ends_i; aa.grid_i = grid_i;

  setup_all<<<70, 256, 0, stream>>>(sa);
  stft_conv<<<NCONV + B * CIN, 256, 0, stream>>>(sc);
  act_grid<<<B, 256, 0, stream>>>(aa);
  pool_proj<<<B * P, 256, 0, stream>>>(feats, ends_i, grid_i, proj_w, proj_b, out_emb);
}

// Round 9
// 248.268 us; speedup vs baseline: 1.1587x; 1.1587x over previous
//
#include <hip/hip_runtime.h>
#include <hip/hip_bf16.h>
#include <hip/hip_fp8.h>
#include <math.h>
#include <string.h>

#define B 32
#define CIN 22
#define T 5000
#define EMB 64
#define P 100
#define HOP 25
#define OC 40
#define FC 120
#define NBIN 11
#define NFR 200

#define TCH 256
#define CROWS 304     // TCH + 24 halo each side
#define RS8 40        // bytes per fp8 xs row (32 channel slots + 8 pad)
#define XROWS 5184    // padded rows per batch in x8t: 24 + T + pad (DMA overshoot safe)

#define XPAD 5128
#define TWROW 24

// planar feats: 3 planes of [B][T][40] bf16
#define PLANE ((size_t)B * T * OC)

typedef __attribute__((ext_vector_type(4))) float f32x4;

__device__ __forceinline__ unsigned short f2bf(float f) {
  unsigned u = __float_as_uint(f);
  unsigned r = (u + 0x7FFFu + ((u >> 16) & 1u)) >> 16;
  return (unsigned short)r;
}
__device__ __forceinline__ float bf2f(unsigned short u) {
  return __uint_as_float(((unsigned)u) << 16);
}
__device__ __forceinline__ unsigned char f2fp8(float f) {
  __hip_fp8_e4m3 q(f);
  return (unsigned char)q.__x;
}
__device__ __forceinline__ float fast_elu(float y) {
  return y > 0.f ? y : (__builtin_amdgcn_exp2f(y * 1.44269504088896340736f) - 1.0f);
}
__device__ __forceinline__ unsigned pack2bf(float a, float b) {
  __hip_bfloat162 h = __float22bfloat162_rn(make_float2(a, b));
  unsigned u;
  memcpy(&u, &h, 4);
  return u;
}
__device__ __forceinline__ float wave_sum_f(float v) {
  #pragma unroll
  for (int off = 1; off < 64; off <<= 1) v += __shfl_xor(v, off);
  return v;
}
__device__ __forceinline__ int wave_sum_i(int v) {
  #pragma unroll
  for (int off = 1; off < 64; off <<= 1) v += __shfl_xor(v, off);
  return v;
}

// ---------------- K1: setup = fp8 weight-pack + twiddles + affine + x8t pre-convert ----------------
struct SetupArgs {
  const float* w1[3]; const float* b1[3]; const float* w2[3]; const float* b2[3];
  const float* g[3];  const float* bt[3]; const float* m[3];  const float* v[3];
  const float* x;
  unsigned char* pw8;
  unsigned char* x8t;               // [B][XROWS][40] fp8, row r = t-(-24); halo/pad zeroed
  float* A; float* Bc; float* tw;   // tw: [128][TWROW]
};

__global__ __launch_bounds__(256) void setup_all(SetupArgs args) {
  int bx = blockIdx.x;
  int tid = threadIdx.x;
  if (bx < 63) {
    // pack fused conv weights into fp8 MFMA A-fragment order.
    int id = bx * 256 + tid;          // fragment-lane id
    if (id < 15936) {                 // 249 fragments * 64 lanes
      int fi = id >> 6;               // global fragment index 0..248
      int lane = id & 63;
      int s, KS, fl;
      if (fi < 27)       { s = 0; KS = 9;  fl = fi; }
      else if (fi < 102) { s = 1; KS = 25; fl = fi - 27; }
      else               { s = 2; KS = 49; fl = fi - 102; }
      int k = fl / 3, ot = fl - k * 3;
      int m = lane & 15, hb = (lane >> 4) << 3;
      int o = ot * 16 + m;
      float val[8];
      #pragma unroll
      for (int j = 0; j < 8; ++j) val[j] = 0.f;
      if (o < OC && hb < CIN) {
        const float* w1 = args.w1[s];
        const float* w2 = args.w2[s];
        if (hb + 8 <= CIN) {          // hb = 0 or 8: all 8 h valid
          for (int i = 0; i < OC; ++i) {
            float wv = w1[i * KS + k];
            const float* w2r = w2 + (size_t)(o * OC + i) * CIN + hb;
            float2 a0 = *(const float2*)(w2r + 0);
            float2 a1 = *(const float2*)(w2r + 2);
            float2 a2 = *(const float2*)(w2r + 4);
            float2 a3 = *(const float2*)(w2r + 6);
            val[0] = fmaf(a0.x, wv, val[0]); val[1] = fmaf(a0.y, wv, val[1]);
            val[2] = fmaf(a1.x, wv, val[2]); val[3] = fmaf(a1.y, wv, val[3]);
            val[4] = fmaf(a2.x, wv, val[4]); val[5] = fmaf(a2.y, wv, val[5]);
            val[6] = fmaf(a3.x, wv, val[6]); val[7] = fmaf(a3.y, wv, val[7]);
          }
        } else {                      // hb = 16: h 16..21 valid (j 0..5)
          for (int i = 0; i < OC; ++i) {
            float wv = w1[i * KS + k];
            const float* w2r = w2 + (size_t)(o * OC + i) * CIN + hb;
            float2 a0 = *(const float2*)(w2r + 0);
            float2 a1 = *(const float2*)(w2r + 2);
            float2 a2 = *(const float2*)(w2r + 4);
            val[0] = fmaf(a0.x, wv, val[0]); val[1] = fmaf(a0.y, wv, val[1]);
            val[2] = fmaf(a1.x, wv, val[2]); val[3] = fmaf(a1.y, wv, val[3]);
            val[4] = fmaf(a2.x, wv, val[4]); val[5] = fmaf(a2.y, wv, val[5]);
          }
        }
      }
      unsigned char bytes[8];
      #pragma unroll
      for (int j = 0; j < 8; ++j) bytes[j] = f2fp8(val[j]);
      long long pk;
      memcpy(&pk, bytes, 8);
      *(long long*)(args.pw8 + (size_t)fi * 512 + lane * 8) = pk;
    }
  } else if (bx < 69) {
    int id = (bx - 63) * 256 + tid;
    if (id < 1408) {
      int n = id & 127, k = id >> 7;
      const double PI = 3.14159265358979323846;
      double ang = -2.0 * PI * (double)((k + 5) * n) / 128.0;
      double win = 0.5 * (1.0 - cos(2.0 * PI * (double)n / 128.0));
      args.tw[n * TWROW + 2 * k]     = (float)(cos(ang) * win);
      args.tw[n * TWROW + 2 * k + 1] = (float)(sin(ang) * win);
    } else if (id < 1536) {
      int n = id - 1408;
      args.tw[n * TWROW + 22] = 0.f;
      args.tw[n * TWROW + 23] = 0.f;
    }
  } else if (bx == 69) {
    if (tid < 120) {
      int s = tid / 40, o = tid - s * 40;
      const float* w2 = args.w2[s];
      float sc = args.g[s][o] / sqrtf(args.v[s][o] + 1e-5f);
      float cc = args.b2[s][o];
      for (int i = 0; i < OC; ++i) {
        float sh = 0.f;
        for (int h = 0; h < CIN; ++h) sh += w2[(o * OC + i) * CIN + h];
        cc = fmaf(args.b1[s][i], sh, cc);
      }
      args.A[tid] = sc;
      args.Bc[tid] = cc * sc + (args.bt[s][o] - args.m[s][o] * sc);
    }
  } else {
    // x8t pre-convert: one thread per padded row. Same f2fp8 on the same
    // values as the old in-kernel staging -> bit-identical fp8 bytes.
    int idx = (bx - 70) * 256 + tid;  // [0, B*XROWS)
    if (idx < B * XROWS) {
      int b = idx / XROWS;
      int ridx = idx - b * XROWS;
      int t = ridx - 24;
      unsigned char row[RS8];
      if (t >= 0 && t < T) {
        const float* xb = args.x + (size_t)b * CIN * T + t;
        #pragma unroll
        for (int ch = 0; ch < CIN; ++ch) row[ch] = f2fp8(xb[(size_t)ch * T]);
        #pragma unroll
        for (int ch = CIN; ch < RS8; ++ch) row[ch] = 0;
      } else {
        #pragma unroll
        for (int ch = 0; ch < RS8; ++ch) row[ch] = 0;
      }
      long long v[5];
      memcpy(v, row, RS8);
      long long* dst = (long long*)(args.x8t + (size_t)idx * RS8);
      dst[0] = v[0]; dst[1] = v[1]; dst[2] = v[2]; dst[3] = v[3]; dst[4] = v[4];
    }
  }
}

// ---------------- K2: STFT power -> comb ----------------
__global__ __launch_bounds__(256) void stft_comb(const float* __restrict__ x,
                                                 const float* __restrict__ tw,
                                                 float* __restrict__ comb) {
  __shared__ float xsh[XPAD];
  int bc = blockIdx.x;
  const float* xr = x + (size_t)bc * T;
  int tid = threadIdx.x;
  for (int i = tid; i < XPAD; i += 256) {
    int mm = i - 64;
    mm = (mm < 0) ? -mm : mm;
    mm = (mm >= T) ? (2 * T - 2 - mm) : mm;
    xsh[i] = xr[mm];
  }
  __syncthreads();
  int fr = tid;
  if (fr < NFR) {
    float cr[NBIN], ci[NBIN];
    #pragma unroll
    for (int k = 0; k < NBIN; ++k) { cr[k] = 0.f; ci[k] = 0.f; }
    const float* xw = xsh + fr * HOP;
    #pragma unroll 2
    for (int n = 0; n < 128; ++n) {
      float xv = xw[n];
      const float4* t4 = reinterpret_cast<const float4*>(tw + n * TWROW);
      float4 w0 = t4[0], w1 = t4[1], w2 = t4[2], w3 = t4[3], w4 = t4[4], w5 = t4[5];
      cr[0] = fmaf(xv, w0.x, cr[0]); ci[0] = fmaf(xv, w0.y, ci[0]);
      cr[1] = fmaf(xv, w0.z, cr[1]); ci[1] = fmaf(xv, w0.w, ci[1]);
      cr[2] = fmaf(xv, w1.x, cr[2]); ci[2] = fmaf(xv, w1.y, ci[2]);
      cr[3] = fmaf(xv, w1.z, cr[3]); ci[3] = fmaf(xv, w1.w, ci[3]);
      cr[4] = fmaf(xv, w2.x, cr[4]); ci[4] = fmaf(xv, w2.y, ci[4]);
      cr[5] = fmaf(xv, w2.z, cr[5]); ci[5] = fmaf(xv, w2.w, ci[5]);
      cr[6] = fmaf(xv, w3.x, cr[6]); ci[6] = fmaf(xv, w3.y, ci[6]);
      cr[7] = fmaf(xv, w3.z, cr[7]); ci[7] = fmaf(xv, w3.w, ci[7]);
      cr[8] = fmaf(xv, w4.x, cr[8]); ci[8] = fmaf(xv, w4.y, ci[8]);
      cr[9] = fmaf(xv, w4.z, cr[9]); ci[9] = fmaf(xv, w4.w, ci[9]);
      cr[10] = fmaf(xv, w5.x, cr[10]); ci[10] = fmaf(xv, w5.y, ci[10]);
    }
    float p[NBIN];
    #pragma unroll
    for (int k = 0; k < NBIN; ++k) p[k] = cr[k] * cr[k] + ci[k] * ci[k];
    float beta = 0.f;
    #pragma unroll
    for (int k = 2; k < NBIN; ++k) beta += p[k];
    comb[bc * NFR + fr] = 0.5f * (p[0] + p[1]) + beta * (1.f / 9.f);
  }
}

// ---------------- K3: mid = act_grid blocks first, then fp8 conv (DMA staging, planar feats) ----------------
struct __align__(16) MidSmem {
  union {
    struct {
      float cl[CIN * NFR];
      float actL[NFR];
      float aiL[P];
      float fL[P];
      int giL[P];
      int sI[P];
      float red;
    } a;
    unsigned char xs8[12288];   // 304-row [t][ch] fp8 tile, padded to 3x1024 per wave
  };
};

template <int KS, int FB, int SBASE>
__device__ __forceinline__ void scale_body(const unsigned char* __restrict__ xs8,
                                           const unsigned char* __restrict__ pw8,
                                           const float* __restrict__ Aff,
                                           const float* __restrict__ Bff,
                                           unsigned short* __restrict__ fplane,
                                           int b, int t0, int wt0, int lane) {
  constexpr int PAD = (KS - 1) / 2;
  const int n = lane & 15, q = lane >> 4;
  f32x4 acc[3][4];
  #pragma unroll
  for (int ot = 0; ot < 3; ++ot)
    #pragma unroll
    for (int ti = 0; ti < 4; ++ti)
      acc[ot][ti] = (f32x4){0.f, 0.f, 0.f, 0.f};

  const unsigned char* pws = pw8 + (size_t)FB * 512 + lane * 8;
  const unsigned char* xrow = xs8 + (24 - PAD + wt0 + n) * RS8 + q * 8;
  // depth-1 software pipeline on BOTH operand streams.
  long long A0 = *(const long long*)(pws);
  long long A1 = *(const long long*)(pws + 512);
  long long A2 = *(const long long*)(pws + 1024);
  long long B0 = *(const long long*)(xrow);
  long long B1 = *(const long long*)(xrow + 16 * RS8);
  long long B2 = *(const long long*)(xrow + 32 * RS8);
  long long B3 = *(const long long*)(xrow + 48 * RS8);
  #pragma unroll 2
  for (int k = 0; k < KS - 1; ++k) {
    const unsigned char* p = pws + (size_t)(k + 1) * 1536;
    long long nA0 = *(const long long*)(p);
    long long nA1 = *(const long long*)(p + 512);
    long long nA2 = *(const long long*)(p + 1024);
    const unsigned char* xr = xrow + (k + 1) * RS8;
    long long nB0 = *(const long long*)(xr);
    long long nB1 = *(const long long*)(xr + 16 * RS8);
    long long nB2 = *(const long long*)(xr + 32 * RS8);
    long long nB3 = *(const long long*)(xr + 48 * RS8);
    acc[0][0] = __builtin_amdgcn_mfma_f32_16x16x32_fp8_fp8(A0, B0, acc[0][0], 0, 0, 0);
    acc[1][0] = __builtin_amdgcn_mfma_f32_16x16x32_fp8_fp8(A1, B0, acc[1][0], 0, 0, 0);
    acc[2][0] = __builtin_amdgcn_mfma_f32_16x16x32_fp8_fp8(A2, B0, acc[2][0], 0, 0, 0);
    acc[0][1] = __builtin_amdgcn_mfma_f32_16x16x32_fp8_fp8(A0, B1, acc[0][1], 0, 0, 0);
    acc[1][1] = __builtin_amdgcn_mfma_f32_16x16x32_fp8_fp8(A1, B1, acc[1][1], 0, 0, 0);
    acc[2][1] = __builtin_amdgcn_mfma_f32_16x16x32_fp8_fp8(A2, B1, acc[2][1], 0, 0, 0);
    acc[0][2] = __builtin_amdgcn_mfma_f32_16x16x32_fp8_fp8(A0, B2, acc[0][2], 0, 0, 0);
    acc[1][2] = __builtin_amdgcn_mfma_f32_16x16x32_fp8_fp8(A1, B2, acc[1][2], 0, 0, 0);
    acc[2][2] = __builtin_amdgcn_mfma_f32_16x16x32_fp8_fp8(A2, B2, acc[2][2], 0, 0, 0);
    acc[0][3] = __builtin_amdgcn_mfma_f32_16x16x32_fp8_fp8(A0, B3, acc[0][3], 0, 0, 0);
    acc[1][3] = __builtin_amdgcn_mfma_f32_16x16x32_fp8_fp8(A1, B3, acc[1][3], 0, 0, 0);
    acc[2][3] = __builtin_amdgcn_mfma_f32_16x16x32_fp8_fp8(A2, B3, acc[2][3], 0, 0, 0);
    A0 = nA0; A1 = nA1; A2 = nA2;
    B0 = nB0; B1 = nB1; B2 = nB2; B3 = nB3;
  }
  // peeled last tap (no prefetch)
  acc[0][0] = __builtin_amdgcn_mfma_f32_16x16x32_fp8_fp8(A0, B0, acc[0][0], 0, 0, 0);
  acc[1][0] = __builtin_amdgcn_mfma_f32_16x16x32_fp8_fp8(A1, B0, acc[1][0], 0, 0, 0);
  acc[2][0] = __builtin_amdgcn_mfma_f32_16x16x32_fp8_fp8(A2, B0, acc[2][0], 0, 0, 0);
  acc[0][1] = __builtin_amdgcn_mfma_f32_16x16x32_fp8_fp8(A0, B1, acc[0][1], 0, 0, 0);
  acc[1][1] = __builtin_amdgcn_mfma_f32_16x16x32_fp8_fp8(A1, B1, acc[1][1], 0, 0, 0);
  acc[2][1] = __builtin_amdgcn_mfma_f32_16x16x32_fp8_fp8(A2, B1, acc[2][1], 0, 0, 0);
  acc[0][2] = __builtin_amdgcn_mfma_f32_16x16x32_fp8_fp8(A0, B2, acc[0][2], 0, 0, 0);
  acc[1][2] = __builtin_amdgcn_mfma_f32_16x16x32_fp8_fp8(A1, B2, acc[1][2], 0, 0, 0);
  acc[2][2] = __builtin_amdgcn_mfma_f32_16x16x32_fp8_fp8(A2, B2, acc[2][2], 0, 0, 0);
  acc[0][3] = __builtin_amdgcn_mfma_f32_16x16x32_fp8_fp8(A0, B3, acc[0][3], 0, 0, 0);
  acc[1][3] = __builtin_amdgcn_mfma_f32_16x16x32_fp8_fp8(A1, B3, acc[1][3], 0, 0, 0);
  acc[2][3] = __builtin_amdgcn_mfma_f32_16x16x32_fp8_fp8(A2, B3, acc[2][3], 0, 0, 0);

  #pragma unroll
  for (int ot = 0; ot < 3; ++ot) {
    int obase = ot * 16 + q * 4;
    if (obase < OC) {
      float Av0 = Aff[SBASE + obase + 0], Bv0 = Bff[SBASE + obase + 0];
      float Av1 = Aff[SBASE + obase + 1], Bv1 = Bff[SBASE + obase + 1];
      float Av2 = Aff[SBASE + obase + 2], Bv2 = Bff[SBASE + obase + 2];
      float Av3 = Aff[SBASE + obase + 3], Bv3 = Bff[SBASE + obase + 3];
      #pragma unroll
      for (int ti = 0; ti < 4; ++ti) {
        int tt = t0 + wt0 + ti * 16 + n;
        if (tt < T) {
          uint2 pk;
          pk.x = pack2bf(fast_elu(fmaf(acc[ot][ti][0], Av0, Bv0)),
                         fast_elu(fmaf(acc[ot][ti][1], Av1, Bv1)));
          pk.y = pack2bf(fast_elu(fmaf(acc[ot][ti][2], Av2, Bv2)),
                         fast_elu(fmaf(acc[ot][ti][3], Av3, Bv3)));
          // planar store: full 80-B rows per scale complete within this epilogue
          *reinterpret_cast<uint2*>(fplane + (size_t)(b * T + tt) * OC + obase) = pk;
        }
      }
    }
  }
}

struct MidArgs {
  const unsigned char* x8t;
  const unsigned char* pw8;
  const float* Aff; const float* Bff;
  unsigned short* feats;
  const float* comb;
  const float* aw1; const float* ab1;
  const float* ag;  const float* abt;
  const float* am;  const float* av;
  const float* aw2; const float* ab2;
  float* out_grid; float* out_acti;
  int* ends_i; int* grid_i;
};

__global__ __launch_bounds__(256) void mid_all(MidArgs args) {
  __shared__ MidSmem sm;
  int bx = blockIdx.x;
  int tid = threadIdx.x;
  if (bx >= B) {
    // ---- conv: 20 chunks of 256 t per batch; 4 waves, 64 t per wave ----
    int cx = bx - B;
    int b = cx / 20, t0 = (cx - b * 20) * TCH;
    // DMA staging: x8t layout matches the LDS tile byte-for-byte (pre-converted,
    // halo pre-zeroed), so 3 wave-level global_load_lds dwordx4 per wave replace
    // the zero-memset + 26 load/convert/ds_write chains per thread.
    {
      int wv = tid >> 6, lane = tid & 63;
      const unsigned char* gsrc = args.x8t + ((size_t)b * XROWS + t0) * RS8;
      #pragma unroll
      for (int c = 0; c < 3; ++c) {
        int off = wv * 3072 + c * 1024;
        __builtin_amdgcn_global_load_lds(
            reinterpret_cast<const unsigned*>(gsrc + off + lane * 16),
            reinterpret_cast<unsigned*>(sm.xs8 + off), 16, 0, 0);
      }
    }
    __syncthreads();
    int wv = tid >> 6, lane = tid & 63;
    int wt0 = wv * 64;
    scale_body<9, 0, 0>(sm.xs8, args.pw8, args.Aff, args.Bff, args.feats, b, t0, wt0, lane);
    scale_body<25, 27, 40>(sm.xs8, args.pw8, args.Aff, args.Bff, args.feats + PLANE, b, t0, wt0, lane);
    scale_body<49, 102, 80>(sm.xs8, args.pw8, args.Aff, args.Bff, args.feats + 2 * PLANE, b, t0, wt0, lane);
  } else {
    // ---- act_grid (fp32, byte-identical to validated pipeline) ----
    int b = bx;
    for (int i = tid; i < CIN * NFR; i += 256) sm.a.cl[i] = args.comb[b * CIN * NFR + i];
    __syncthreads();
    int t = tid;
    if (t < NFR) {
      float z = args.ab2[0];
      for (int o = 0; o < 11; ++o) {
        float s = args.ab1[o];
        for (int i = 0; i < CIN; ++i) {
          const float* wr = args.aw1 + o * 66 + i * 3;
          const float* crow = sm.a.cl + i * NFR;
          if (t > 0)       s = fmaf(wr[0], crow[t - 1], s);
          s = fmaf(wr[1], crow[t], s);
          if (t < NFR - 1) s = fmaf(wr[2], crow[t + 1], s);
        }
        float rs = 1.0f / sqrtf(args.av[o] + 1e-5f);
        float y = (s - args.am[o]) * rs * args.ag[o] + args.abt[o];
        y = fmaxf(y, 0.f);
        z = fmaf(args.aw2[o], y, z);
      }
      sm.a.actL[t] = 1.f / (1.f + expf(-z));
    }
    __syncthreads();
    if (t < P) {
      float ai = 0.5f * (sm.a.actL[2 * t] + sm.a.actL[2 * t + 1]);
      sm.a.aiL[t] = ai;
      args.out_acti[b * P + t] = ai;
      sm.a.fL[t] = 1.f / (ai + 1e-6f);
    }
    __syncthreads();
    if (t < 64) {
      float v = sm.a.fL[t] + ((t + 64 < P) ? sm.a.fL[t + 64] : 0.f);
      v = wave_sum_f(v);
      if (t == 0) sm.a.red = v;
    }
    __syncthreads();
    float sw = sm.a.red;
    if (t < P) {
      float ggv = (sm.a.fL[t] / sw) * 5000.f;
      ggv = fminf(fmaxf(ggv, 10.f), 100.f);
      sm.a.fL[t] = ggv;
    }
    __syncthreads();
    if (t < 64) {
      float v = sm.a.fL[t] + ((t + 64 < P) ? sm.a.fL[t + 64] : 0.f);
      v = wave_sum_f(v);
      if (t == 0) sm.a.red = v;
    }
    __syncthreads();
    float r = 5000.f / sm.a.red;
    if (t < P) sm.a.giL[t] = (int)rintf(sm.a.fL[t] * r);
    __syncthreads();
    if (t < 64) {
      int v = sm.a.giL[t] + ((t + 64 < P) ? sm.a.giL[t + 64] : 0);
      v = wave_sum_i(v);
      if (t == 0) sm.a.red = __int_as_float(v);
    }
    __syncthreads();
    if (t == P - 1) sm.a.giL[P - 1] += 5000 - __float_as_int(sm.a.red);
    __syncthreads();
    if (t < P) sm.a.giL[t] = min(max(sm.a.giL[t], 10), 100);
    __syncthreads();
    if (t < 64) {
      int v = sm.a.giL[t] + ((t + 64 < P) ? sm.a.giL[t + 64] : 0);
      v = wave_sum_i(v);
      if (t == 0) sm.a.red = __int_as_float(v);
    }
    __syncthreads();
    if (t == P - 1) sm.a.giL[P - 1] += 5000 - __float_as_int(sm.a.red);
    __syncthreads();
    if (t < P) sm.a.sI[t] = max(sm.a.giL[t], 10);
    __syncthreads();
    #pragma unroll
    for (int off = 1; off < P; off <<= 1) {
      int v = 0;
      if (t < P && t >= off) v = sm.a.sI[t - off];
      __syncthreads();
      if (t < P) sm.a.sI[t] += v;
      __syncthreads();
    }
    if (t < P) {
      int g2 = max(sm.a.giL[t], 10);
      args.out_grid[b * P + t] = (float)g2;
      args.grid_i[b * P + t] = g2;
      args.ends_i[b * P + t] = sm.a.sI[t];
    }
  }
}

// ---------------- K4: ragged avg+max pool + projection (planar feats) ----------------
__global__ __launch_bounds__(256) void pool_proj(const unsigned short* __restrict__ feats,
                                                 const int* __restrict__ ends_i,
                                                 const int* __restrict__ grid_i,
                                                 const float* __restrict__ proj_w,
                                                 const float* __restrict__ proj_b,
                                                 float* __restrict__ out_emb) {
  int bp = blockIdx.x;
  int b = bp / P;
  int end = ends_i[bp];
  int gr = grid_i[bp];
  int start = end - gr;
  __shared__ float lds_s[16 * FC];
  __shared__ float lds_m[16 * FC];
  __shared__ float pooled[FC];
  int tid = threadIdx.x;
  bool valid = (end <= T);
  int g = tid % 15;
  int r = tid / 15;
  if (valid && r < 16) {
    float s[8], m[8];
    #pragma unroll
    for (int j = 0; j < 8; ++j) { s[j] = 0.f; m[j] = -INFINITY; }
    // plane = g/5, channel offset within plane = (g%5)*8; logical channel
    // index g*8+j is unchanged vs the interleaved layout.
    int pl = g / 5, g2 = g - pl * 5;
    const unsigned short* base = feats + (size_t)pl * PLANE + (size_t)(b * T + start) * OC + g2 * 8;
    for (int i = r; i < gr; i += 16) {
      uint4 u4 = *reinterpret_cast<const uint4*>(base + (size_t)i * OC);
      unsigned w[4] = {u4.x, u4.y, u4.z, u4.w};
      #pragma unroll
      for (int j = 0; j < 4; ++j) {
        float v0 = bf2f((unsigned short)(w[j] & 0xffffu));
        float v1 = bf2f((unsigned short)(w[j] >> 16));
        s[2 * j] += v0; s[2 * j + 1] += v1;
        m[2 * j] = fmaxf(m[2 * j], v0); m[2 * j + 1] = fmaxf(m[2 * j + 1], v1);
      }
    }
    #pragma unroll
    for (int j = 0; j < 8; ++j) {
      lds_s[r * FC + g * 8 + j] = s[j];
      lds_m[r * FC + g * 8 + j] = m[j];
    }
  }
  __syncthreads();
  if (tid < FC) {
    if (valid) {
      float s = 0.f, mx = -INFINITY;
      #pragma unroll
      for (int rr = 0; rr < 16; ++rr) {
        s += lds_s[rr * FC + tid];
        mx = fmaxf(mx, lds_m[rr * FC + tid]);
      }
      pooled[tid] = s / (float)gr + mx;
    } else {
      pooled[tid] = 0.f;
    }
  }
  __syncthreads();
  if (tid < EMB) {
    float e = proj_b[tid];
    const float* wr = proj_w + tid * FC;
    #pragma unroll 8
    for (int c = 0; c < FC; ++c) e = fmaf(wr[c], pooled[c], e);
    out_emb[(size_t)bp * EMB + tid] = e;
  }
}

extern "C" void kernel_launch(void* const* d_in, const int* in_sizes, int n_in,
                              void* d_out, int out_size, void* d_ws, size_t ws_size,
                              hipStream_t stream) {
  const float* x = (const float*)d_in[0];
  const float* aw1 = (const float*)d_in[25];
  const float* ab1 = (const float*)d_in[26];
  const float* ag  = (const float*)d_in[27];
  const float* abt = (const float*)d_in[28];
  const float* am  = (const float*)d_in[29];
  const float* av  = (const float*)d_in[30];
  const float* aw2 = (const float*)d_in[31];
  const float* ab2 = (const float*)d_in[32];
  const float* proj_w = (const float*)d_in[33];
  const float* proj_b = (const float*)d_in[34];

  float* wsf = (float*)d_ws;
  float* A    = wsf;                 // 120
  float* Bc   = wsf + 120;           // 120
  float* tw   = wsf + 240;           // 3072
  float* comb = wsf + 4096;          // 140800
  int* ends_i = (int*)(wsf + 144896);
  int* grid_i = (int*)(wsf + 148096);
  unsigned char* pw8 = (unsigned char*)(wsf + 151296);      // 127488 bytes (8B-aligned)
  unsigned short* feats = (unsigned short*)(wsf + 215040);  // 3 planes x B*T*40 bf16 (38.4 MB)
  unsigned char* x8t = (unsigned char*)(feats + 3 * PLANE); // B*XROWS*40 fp8 (6.64 MB), 16B-aligned

  float* out      = (float*)d_out;
  float* out_emb  = out;
  float* out_grid = out + 204800;
  float* out_acti = out + 208000;

  SetupArgs sa;
  for (int s = 0; s < 3; ++s) {
    sa.w1[s] = (const float*)d_in[1 + 8 * s];
    sa.b1[s] = (const float*)d_in[2 + 8 * s];
    sa.w2[s] = (const float*)d_in[3 + 8 * s];
    sa.b2[s] = (const float*)d_in[4 + 8 * s];
    sa.g[s]  = (const float*)d_in[5 + 8 * s];
    sa.bt[s] = (const float*)d_in[6 + 8 * s];
    sa.m[s]  = (const float*)d_in[7 + 8 * s];
    sa.v[s]  = (const float*)d_in[8 + 8 * s];
  }
  sa.x = x; sa.pw8 = pw8; sa.x8t = x8t; sa.A = A; sa.Bc = Bc; sa.tw = tw;

  MidArgs ma;
  ma.x8t = x8t; ma.pw8 = pw8; ma.Aff = A; ma.Bff = Bc; ma.feats = feats;
  ma.comb = comb; ma.aw1 = aw1; ma.ab1 = ab1; ma.ag = ag; ma.abt = abt;
  ma.am = am; ma.av = av; ma.aw2 = aw2; ma.ab2 = ab2;
  ma.out_grid = out_grid; ma.out_acti = out_acti;
  ma.ends_i = ends_i; ma.grid_i = grid_i;

  int xblocks = (B * XROWS + 255) / 256;   // 648
  setup_all<<<70 + xblocks, 256, 0, stream>>>(sa);
  stft_comb<<<B * CIN, 256, 0, stream>>>(x, tw, comb);
  mid_all<<<B + 20 * B, 256, 0, stream>>>(ma);
  pool_proj<<<B * P, 256, 0, stream>>>(feats, ends_i, grid_i, proj_w, proj_b, out_emb);
}